// Round 3
// baseline (14547.917 us; speedup 1.0000x reference)
//
#include <hip/hip_runtime.h>
#include <hip/hip_bf16.h>
#include <math.h>

#define B 256
#define S 128
#define I_DIM 512
#define H 1024
#define C 10
#define WROW 1536

#define NBLK 256
#define NBLK_DIR 128
#define SMEM_W_BYTES (64 * 2048)           // 64 n-rows x 1024 k bf16, swizzled
#define SMEM_TOTAL   (SMEM_W_BYTES + 8 * 512)  // + 8 waves x 512B h-staging

typedef float f32x4 __attribute__((ext_vector_type(4)));
typedef float f32x2 __attribute__((ext_vector_type(2)));
typedef __bf16 bf16x8 __attribute__((ext_vector_type(8)));

__device__ __forceinline__ unsigned short f2bf(float f) {
    union { float f; unsigned u; } a; a.f = f;
    return (unsigned short)((a.u + 0x7fffu + ((a.u >> 16) & 1u)) >> 16);
}
__device__ __forceinline__ float sigf(float v) { return 1.0f / (1.0f + __expf(-v)); }
__device__ __forceinline__ float tanh_fast(float v) { return 1.0f - 2.0f / (1.0f + __expf(2.0f * v)); }

// projP[d][jt][v][jj][g] = embed[v] . Wx_d[g*1024 + jt*16 + jj] + b_d[...]
__global__ void proj_kernel(const float* __restrict__ embed,
                            const float* __restrict__ fwd_W,
                            const float* __restrict__ fwd_b,
                            const float* __restrict__ bwd_W,
                            const float* __restrict__ bwd_b,
                            float* __restrict__ projP) {
    __shared__ float wrows[16][516];
    int d  = blockIdx.x >> 8;
    int nc = blockIdx.x & 255;
    int n0 = nc * 16;
    const float* W    = d ? bwd_W : fwd_W;
    const float* bias = d ? bwd_b : fwd_b;
    int tid = threadIdx.x;
    for (int idx = tid; idx < 16 * 512; idx += 256) {
        int r = idx >> 9, k = idx & 511;
        wrows[r][k] = W[(n0 + r) * WROW + k];
    }
    __syncthreads();
    for (int o = tid; o < 128 * 16; o += 256) {
        int v = o >> 4, r = o & 15;
        const float* er = embed + v * I_DIM;
        float s = bias[n0 + r];
        for (int k = 0; k < I_DIM; k++) s += er[k] * wrows[r][k];
        int n = n0 + r;
        int g = n >> 10, jrem = n & 1023;
        int jtl = jrem >> 4, jj = jrem & 15;
        projP[(((size_t)(d * 64 + jtl)) * 128 + v) * 64 + jj * 4 + g] = s;
    }
}

// Persistent bi-LSTM: 256 blocks x 512 threads (8 waves, 2/SIMD).
// block=(d, bh, jt): jt owns 64 gate-interleaved n-rows (16 j x 4 gates), bh = 128-b half.
// wave (wr 0..3, wc 0..1): 32 b x 32 n. Custom per-(step,dir) barrier in ws.
__global__ __launch_bounds__(512, 2) void bilstm_persistent(
        const int* __restrict__ x,
        const float* __restrict__ fwd_W,
        const float* __restrict__ bwd_W,
        const float* __restrict__ projP,
        const float* __restrict__ p_w,
        const float* __restrict__ p_b,
        __hip_bfloat16* __restrict__ hbuf,  // [2 parity][2 d][256 b][1024 j]
        float* __restrict__ hf,             // [2 d][256 b][1024 j]
        unsigned* __restrict__ bar,         // [S][2] slots, stride 32 u32
        float* __restrict__ out) {
    extern __shared__ char smem[];
    unsigned short* hstage = (unsigned short*)(smem + SMEM_W_BYTES);

    const int bid = blockIdx.x;
    const int d  = bid >> 7;
    const int bh = (bid >> 6) & 1;
    const int jt = bid & 63;
    const int tid = threadIdx.x;
    const int wid = tid >> 6, lane = tid & 63;
    const int wc = wid & 1, wr = wid >> 1;
    const int l15 = lane & 15, l4 = lane >> 4;

    const float* W = d ? bwd_W : fwd_W;

    // ---- stage Wh slice into LDS (bf16, gate-interleaved, XOR-swizzled) ----
    for (int n = 0; n < 64; n++) {
        int g = n & 3, jj = n >> 2;
        f32x2 v = *(const f32x2*)(W + (size_t)(g * 1024 + jt * 16 + jj) * WROW + I_DIM + tid * 2);
        *(ushort2*)(smem + n * 2048 + ((tid * 4) ^ ((n & 7) << 4))) =
            make_ushort2(f2bf(v[0]), f2bf(v[1]));
    }
    __syncthreads();

    int abase[2], aswz[2];
#pragma unroll
    for (int i2 = 0; i2 < 2; i2++) {
        int row = wc * 32 + i2 * 16 + l15;
        abase[i2] = row * 2048;
        aswz[i2]  = (row & 7) << 4;
    }
    int bglob[2]; size_t hoff[2];
#pragma unroll
    for (int jf = 0; jf < 2; jf++) {
        bglob[jf] = bh * 128 + wr * 32 + jf * 16 + l15;
        hoff[jf] = (size_t)bglob[jf] * H;
    }
    const size_t dHB = (size_t)d * B * H;
    const float* pbase = projP + (size_t)(d * 64 + jt) * (128 * 64);
    unsigned short* hst = hstage + wid * 256;

    float cst[2][2] = {};
    f32x4 pj[2][2];
    int vv[2];
    {   // prefetch x/proj for t=0
        int tt = d ? (S - 1) : 0;
        vv[0] = x[bglob[0] * S + tt];
        vv[1] = x[bglob[1] * S + tt];
#pragma unroll
        for (int i2 = 0; i2 < 2; i2++)
#pragma unroll
            for (int jf = 0; jf < 2; jf++)
                pj[i2][jf] = *(const f32x4*)(pbase + (size_t)vv[jf] * 64 + (wc * 8 + i2 * 4 + l4) * 4);
    }

    for (int t = 0; t < S; t++) {
        if (t > 0) {
            if (tid == 0) {
                const unsigned* p = bar + ((t - 1) * 2 + d) * 32;
                while (__hip_atomic_load(p, __ATOMIC_RELAXED, __HIP_MEMORY_SCOPE_AGENT) < NBLK_DIR)
                    __builtin_amdgcn_s_sleep(2);
            }
            __syncthreads();
            __threadfence();
        }

        f32x4 acc[2][2] = {};
        if (t > 0) {
            const __hip_bfloat16* hr = hbuf + (size_t)(t & 1) * 2 * B * H + dHB;
            bf16x8 Ap[2][2], Bp[4][2];
#pragma unroll
            for (int p = 0; p < 2; p++)
#pragma unroll
                for (int i2 = 0; i2 < 2; i2++)
                    Ap[p][i2] = *(const bf16x8*)(smem + abase[i2] + ((p * 64 + l4 * 16) ^ aswz[i2]));
#pragma unroll
            for (int p = 0; p < 4; p++)
#pragma unroll
                for (int jf = 0; jf < 2; jf++)
                    Bp[p][jf] = *(const bf16x8*)(hr + hoff[jf] + p * 32 + l4 * 8);
#pragma unroll
            for (int kk = 0; kk < 32; kk++) {
                bf16x8 a0 = Ap[kk & 1][0], a1 = Ap[kk & 1][1];
                bf16x8 b0 = Bp[kk & 3][0], b1 = Bp[kk & 3][1];
                if (kk < 30) {
                    Ap[kk & 1][0] = *(const bf16x8*)(smem + abase[0] + (((kk + 2) * 64 + l4 * 16) ^ aswz[0]));
                    Ap[kk & 1][1] = *(const bf16x8*)(smem + abase[1] + (((kk + 2) * 64 + l4 * 16) ^ aswz[1]));
                }
                if (kk < 28) {
                    Bp[kk & 3][0] = *(const bf16x8*)(hr + hoff[0] + (kk + 4) * 32 + l4 * 8);
                    Bp[kk & 3][1] = *(const bf16x8*)(hr + hoff[1] + (kk + 4) * 32 + l4 * 8);
                }
                acc[0][0] = __builtin_amdgcn_mfma_f32_16x16x32_bf16(a0, b0, acc[0][0], 0, 0, 0);
                acc[0][1] = __builtin_amdgcn_mfma_f32_16x16x32_bf16(a0, b1, acc[0][1], 0, 0, 0);
                acc[1][0] = __builtin_amdgcn_mfma_f32_16x16x32_bf16(a1, b0, acc[1][0], 0, 0, 0);
                acc[1][1] = __builtin_amdgcn_mfma_f32_16x16x32_bf16(a1, b1, acc[1][1], 0, 0, 0);
            }
        }

        // gates: lane owns (jj = wc*8+i2*4+l4, b = bglob[jf]); 4 gates in acc regs
#pragma unroll
        for (int i2 = 0; i2 < 2; i2++) {
#pragma unroll
            for (int jf = 0; jf < 2; jf++) {
                float zg = acc[i2][jf][0] + pj[i2][jf][0];
                float zi = acc[i2][jf][1] + pj[i2][jf][1];
                float zf = acc[i2][jf][2] + pj[i2][jf][2];
                float zo = acc[i2][jf][3] + pj[i2][jf][3];
                float gg = tanh_fast(zg);
                float ii = sigf(zi);
                float ff = sigf(zf);
                float oo = sigf(zo);
                float cn = gg * ii + cst[i2][jf] * ff;
                cst[i2][jf] = cn;
                float hn = tanh_fast(cn) * oo;
                hst[(jf * 16 + l15) * 8 + i2 * 4 + l4] = f2bf(hn);
                if (t == S - 1)
                    hf[dHB + hoff[jf] + jt * 16 + wc * 8 + i2 * 4 + l4] = hn;
            }
        }

        // wave-local LDS -> coalesced global h store
        {
            uint2 hv = *(const uint2*)((const char*)hst + lane * 8);
            __hip_bfloat16* hw = hbuf + (size_t)((t + 1) & 1) * 2 * B * H + dHB;
            *(uint2*)(hw + (size_t)(bh * 128 + wr * 32 + (lane >> 1)) * H + jt * 16 + wc * 8 + (lane & 1) * 4) = hv;
        }
        __threadfence();
        __syncthreads();
        if (tid == 0) atomicAdd(bar + (t * 2 + d) * 32, 1u);

        // prefetch x/proj for t+1 (overlaps next barrier wait)
        if (t + 1 < S) {
            int tt = d ? (S - 2 - t) : (t + 1);
            vv[0] = x[bglob[0] * S + tt];
            vv[1] = x[bglob[1] * S + tt];
#pragma unroll
            for (int i2 = 0; i2 < 2; i2++)
#pragma unroll
                for (int jf = 0; jf < 2; jf++)
                    pj[i2][jf] = *(const f32x4*)(pbase + (size_t)vv[jf] * 64 + (wc * 8 + i2 * 4 + l4) * 4);
        }
    }

    // wait for the OTHER direction's final step, then head
    if (tid == 0) {
        const unsigned* p = bar + ((S - 1) * 2 + (1 - d)) * 32;
        while (__hip_atomic_load(p, __ATOMIC_RELAXED, __HIP_MEMORY_SCOPE_AGENT) < NBLK_DIR)
            __builtin_amdgcn_s_sleep(2);
    }
    __syncthreads();
    __threadfence();

    if (tid < 64) {
        int b = bid;
        float part[C];
#pragma unroll
        for (int cc = 0; cc < C; cc++) part[cc] = 0.0f;
        for (int jj = tid; jj < 2 * H; jj += 64) {
            float hv = (jj < H) ? hf[(size_t)b * H + jj]
                                : hf[(size_t)B * H + (size_t)b * H + jj - H];
#pragma unroll
            for (int cc = 0; cc < C; cc++) part[cc] += hv * p_w[cc * 2 * H + jj];
        }
#pragma unroll
        for (int cc = 0; cc < C; cc++) {
            float v = part[cc];
            for (int off = 32; off; off >>= 1) v += __shfl_down(v, off);
            part[cc] = v;
        }
        if (tid == 0) {
            float lg[C];
            float m = -1e30f;
            for (int cc = 0; cc < C; cc++) {
                lg[cc] = part[cc] + p_b[cc];
                m = fmaxf(m, lg[cc]);
            }
            float s = 0.0f;
            for (int cc = 0; cc < C; cc++) s += expf(lg[cc] - m);
            float lse = logf(s) + m;
            for (int cc = 0; cc < C; cc++) out[b * C + cc] = lg[cc] - lse;
        }
    }
}

extern "C" void kernel_launch(void* const* d_in, const int* in_sizes, int n_in,
                              void* d_out, int out_size, void* d_ws, size_t ws_size,
                              hipStream_t stream) {
    const int*   x     = (const int*)d_in[0];
    const float* embed = (const float*)d_in[1];
    const float* fwd_W = (const float*)d_in[2];
    const float* fwd_b = (const float*)d_in[3];
    const float* bwd_W = (const float*)d_in[4];
    const float* bwd_b = (const float*)d_in[5];
    const float* p_w   = (const float*)d_in[6];
    const float* p_b   = (const float*)d_in[7];
    float* outp = (float*)d_out;

    char* ws = (char*)d_ws;
    float* projP = (float*)ws;                  ws += (size_t)2 * 64 * 128 * 64 * 4;  // 4 MB
    __hip_bfloat16* hbuf = (__hip_bfloat16*)ws; ws += (size_t)2 * 2 * B * H * 2;      // 2 MB
    float* hfb = (float*)ws;                    ws += (size_t)2 * B * H * 4;          // 2 MB
    unsigned* bar = (unsigned*)ws;              ws += (size_t)S * 2 * 32 * 4;         // 32 KB

    hipMemsetAsync(bar, 0, (size_t)S * 2 * 32 * 4, stream);
    hipLaunchKernelGGL(proj_kernel, dim3(512), dim3(256), 0, stream,
                       embed, fwd_W, fwd_b, bwd_W, bwd_b, projP);

    hipFuncSetAttribute((const void*)bilstm_persistent,
                        hipFuncAttributeMaxDynamicSharedMemorySize, SMEM_TOTAL);

    void* args[] = {(void*)&x, (void*)&fwd_W, (void*)&bwd_W, (void*)&projP,
                    (void*)&p_w, (void*)&p_b, (void*)&hbuf, (void*)&hfb,
                    (void*)&bar, (void*)&outp};
    hipLaunchCooperativeKernel((void*)bilstm_persistent, dim3(NBLK), dim3(512),
                               args, SMEM_TOTAL, stream);
}